// Round 9
// baseline (202.564 us; speedup 1.0000x reference)
//
#include <hip/hip_runtime.h>
#include <hip/hip_bf16.h>

// DARTS MixedOp. B=64, C=128, H=W=32. Per-sample top-k(2) masked-softmax gate
// over 8 ops. Inputs fp32, outputs fp32.
//
// R9: pw GEMMs restructured. Orientation m=hw, n=co: B-operand (W, bf16 via
// k_prep) loaded DIRECT from global (L2-hot, no LDS); A-operand = transposed
// In tile in LDS with LROW=130 (bank-stride 1: u16 transpose writes 2-way
// free, b32 frag reads ~2-way). gate*BN folded into Bt staging. D rows = hw
// -> float4 RMW stores. LDS 16.6KB/block. dw/pools unchanged (proven).
//
// ws: gates @0 | cnum @2048 | cops @2304 | Wbf[6][128][128] bf16 @4096 |
// 8 bf16 bufs of 16.8MB @200704 (A4 A5 B4 B5 P4 P5 P6 P7).

#define BN_SCALE 0.9999950000374997f  // 1/sqrt(1+1e-5)
#define BB 64
#define CC 128
#define HH 32
#define WW 32
#define PLANE (HH*WW)          // 1024
#define SAMP (CC*PLANE)        // 131072
#define NOUT0 (BB*SAMP)        // 8388608

typedef __attribute__((ext_vector_type(8))) short bf16x8;
typedef __attribute__((ext_vector_type(4))) float f32x4;

__device__ __forceinline__ float us2f(unsigned int u) {
    unsigned int x = (u & 0xffffu) << 16;
    float f; __builtin_memcpy(&f, &x, 4); return f;
}
__device__ __forceinline__ unsigned short f2us(float f) {
    __hip_bfloat16 h = __float2bfloat16(f);
    unsigned short u; __builtin_memcpy(&u, &h, 2); return u;
}

// ---------------------------------------------------------------- gates
__global__ void k_gates(const float* __restrict__ wlog,
                        const void* __restrict__ topp,
                        float* __restrict__ gates,
                        int* __restrict__ cnum, int* __restrict__ cops,
                        float* __restrict__ out_w) {
    int b = threadIdx.x;                    // block is exactly 64 threads

    int top = -1;                           // robust `top` parse
    {
        unsigned int u0 = *(const unsigned int*)topp;
        int i32 = (int)u0;
        if (i32 >= 1 && i32 <= 8) top = i32;
        else {
            float f32; __builtin_memcpy(&f32, &u0, 4);
            if (f32 >= 1.f && f32 <= 8.f) top = (int)(f32 + 0.5f);
            else { float fb = us2f(u0); if (fb >= 1.f && fb <= 8.f) top = (int)(fb + 0.5f); }
        }
        if (top < 1 || top > 8) top = 2;
    }

    float lw[8];
    #pragma unroll
    for (int i = 0; i < 8; ++i) {
        lw[i] = wlog[b * 8 + i];
        out_w[b * 8 + i] = lw[i];           // output 1: clone of logits
    }
    bool sel[8] = {false,false,false,false,false,false,false,false};
    for (int t = 0; t < top; ++t) {         // lax.top_k tie-break: lowest index
        int best = -1; float bv = -3.4e38f;
        #pragma unroll
        for (int i = 0; i < 8; ++i)
            if (!sel[i] && lw[i] > bv) { bv = lw[i]; best = i; }
        if (best >= 0) sel[best] = true;
    }
    float m = -3.4e38f;
    #pragma unroll
    for (int i = 0; i < 8; ++i) if (sel[i] && lw[i] > m) m = lw[i];
    float s = 0.f, e[8];
    #pragma unroll
    for (int i = 0; i < 8; ++i) { e[i] = sel[i] ? expf(lw[i] - m) : 0.f; s += e[i]; }
    float inv = (s > 0.f) ? 1.f / s : 0.f;
    float g[8];
    #pragma unroll
    for (int i = 0; i < 8; ++i) {
        g[i] = (s > 0.f) ? e[i] * inv : (sel[i] ? 1.f / (float)top : 0.f);
        gates[b * 8 + i] = g[i];
    }
    int n = 0;
    #pragma unroll
    for (int i = 4; i < 8; ++i)
        if (g[i] > 0.f) { if (n < 4) cops[b * 4 + n] = i; ++n; }
    cnum[b] = (n < 4) ? n : 4;
}

// ------------------------ weight prep: 6 pw matrices fp32 -> bf16 in ws
__global__ __launch_bounds__(256) void
k_prep(const float* __restrict__ w0, const float* __restrict__ w1,
       const float* __restrict__ w2, const float* __restrict__ w3,
       const float* __restrict__ w4, const float* __restrict__ w5,
       unsigned short* __restrict__ Wbf) {
    int idx = blockIdx.x * 256 + threadIdx.x;   // 6*16384
    int mat = idx >> 14, e = idx & 16383;
    const float* src; float s = 1.f;
    switch (mat) {                               // block-uniform
        case 0:  src = w0; s = BN_SCALE; break;  // sc3_p1 (mid, BN folded)
        case 1:  src = w1; s = BN_SCALE; break;  // sc5_p1
        case 2:  src = w2; break;                // sc3_p2 (final, gs in Bt)
        case 3:  src = w3; break;                // sc5_p2
        case 4:  src = w4; break;                // dc3_p
        default: src = w5; break;                // dc5_p
    }
    Wbf[idx] = f2us(src[e] * s);
}

// ------------------------------- pools + skip + out init (R5, proven)
__global__ __launch_bounds__(256) void
k_pools(const float* __restrict__ x,
        const float* __restrict__ gates,
        float* __restrict__ out) {
    int plane = blockIdx.x;            // b*128 + c
    int b = plane >> 7;
    float g1 = gates[b * 8 + 1] * BN_SCALE;
    float g2 = gates[b * 8 + 2] * BN_SCALE;
    float g3 = gates[b * 8 + 3];
    float* op = out + (size_t)plane * PLANE;
    if (g1 == 0.f && g2 == 0.f && g3 == 0.f) {
        ((float4*)op)[threadIdx.x] = make_float4(0.f, 0.f, 0.f, 0.f);
        return;
    }
    __shared__ float sx[PLANE];
    ((float4*)sx)[threadIdx.x] = ((const float4*)(x + (size_t)plane * PLANE))[threadIdx.x];
    __syncthreads();
    #pragma unroll
    for (int j = 0; j < 4; ++j) {
        int px = threadIdx.x + j * 256;
        int h = px >> 5, w = px & 31;
        float mx = -3.4e38f, sm = 0.f;
        int cnt = 0;
        #pragma unroll
        for (int dh = -1; dh <= 1; ++dh) {
            int ih = h + dh;
            if ((unsigned)ih >= HH) continue;
            #pragma unroll
            for (int dw = -1; dw <= 1; ++dw) {
                int iw = w + dw;
                if ((unsigned)iw >= WW) continue;
                float v = sx[ih * WW + iw];
                mx = fmaxf(mx, v);
                sm += v;
                ++cnt;
            }
        }
        op[px] = g1 * mx + g2 * (sm / (float)cnt) + g3 * sx[px];
    }
}

// ------------------------------------------- depthwise conv helper
template <int K, int DIL>
__device__ __forceinline__ void dw_comp(const float* __restrict__ sx,
                                        const float* __restrict__ wd, int c,
                                        unsigned short* __restrict__ opp) {
    constexpr int PAD = (K / 2) * DIL;
    float wk[K * K];
    #pragma unroll
    for (int i = 0; i < K * K; ++i) wk[i] = wd[c * K * K + i];
    #pragma unroll
    for (int j = 0; j < 4; ++j) {
        int px = threadIdx.x + j * 256;
        int h = px >> 5, w = px & 31;
        float acc = 0.f;
        #pragma unroll
        for (int ky = 0; ky < K; ++ky) {
            int ih = h + ky * DIL - PAD;
            if ((unsigned)ih >= HH) continue;
            #pragma unroll
            for (int kx = 0; kx < K; ++kx) {
                int iw = w + kx * DIL - PAD;
                if ((unsigned)iw >= WW) continue;
                acc = fmaf(wk[ky * K + kx], sx[ih * WW + iw], acc);
            }
        }
        opp[px] = f2us(acc);
    }
}

// ---------------------------------- first dw for all 4 conv ops (from x)
__global__ __launch_bounds__(256) void
k_dw_first(const float* __restrict__ x,
           const float* __restrict__ w4, const float* __restrict__ w5,
           const float* __restrict__ w6, const float* __restrict__ w7,
           const float* __restrict__ gates,
           unsigned short* __restrict__ A4, unsigned short* __restrict__ A5,
           unsigned short* __restrict__ P6, unsigned short* __restrict__ P7) {
    int plane = blockIdx.x;            // b*128 + c
    int b = plane >> 7, c = plane & 127;
    float g4 = gates[b * 8 + 4], g5 = gates[b * 8 + 5];
    float g6 = gates[b * 8 + 6], g7 = gates[b * 8 + 7];
    if (g4 == 0.f && g5 == 0.f && g6 == 0.f && g7 == 0.f) return;
    __shared__ float sx[PLANE];
    {
        float4 v = ((const float4*)(x + (size_t)plane * PLANE))[threadIdx.x];
        ((float4*)sx)[threadIdx.x] =
            make_float4(fmaxf(v.x, 0.f), fmaxf(v.y, 0.f),
                        fmaxf(v.z, 0.f), fmaxf(v.w, 0.f));
    }
    __syncthreads();
    size_t off = (size_t)plane * PLANE;
    if (g4 != 0.f) dw_comp<3, 1>(sx, w4, c, A4 + off);
    if (g5 != 0.f) dw_comp<5, 1>(sx, w5, c, A5 + off);
    if (g6 != 0.f) dw_comp<3, 2>(sx, w6, c, P6 + off);
    if (g7 != 0.f) dw_comp<5, 2>(sx, w7, c, P7 + off);
}

// ---------------------------------- second dw for sep ops (from bufB)
__global__ __launch_bounds__(256) void
k_dw_second(const unsigned short* __restrict__ B4,
            const unsigned short* __restrict__ B5,
            const float* __restrict__ w4, const float* __restrict__ w5,
            const float* __restrict__ gates,
            unsigned short* __restrict__ P4, unsigned short* __restrict__ P5) {
    int plane = blockIdx.x;            // b*128 + c
    int b = plane >> 7, c = plane & 127;
    float g4 = gates[b * 8 + 4], g5 = gates[b * 8 + 5];
    if (g4 == 0.f && g5 == 0.f) return;
    __shared__ float sx[PLANE];
    size_t off = (size_t)plane * PLANE;
    if (g4 != 0.f) {                       // block-uniform branch
        ushort4 v = ((const ushort4*)(B4 + off))[threadIdx.x];
        ((float4*)sx)[threadIdx.x] =
            make_float4(fmaxf(us2f(v.x), 0.f), fmaxf(us2f(v.y), 0.f),
                        fmaxf(us2f(v.z), 0.f), fmaxf(us2f(v.w), 0.f));
        __syncthreads();
        dw_comp<3, 1>(sx, w4, c, P4 + off);
        __syncthreads();
    }
    if (g5 != 0.f) {
        ushort4 v = ((const ushort4*)(B5 + off))[threadIdx.x];
        ((float4*)sx)[threadIdx.x] =
            make_float4(fmaxf(us2f(v.x), 0.f), fmaxf(us2f(v.y), 0.f),
                        fmaxf(us2f(v.z), 0.f), fmaxf(us2f(v.w), 0.f));
        __syncthreads();
        dw_comp<5, 1>(sx, w5, c, P5 + off);
    }
}

// ---------------- MFMA pw building blocks --------------------------------
// Orientation: m=hw, n=co. A = In^T tile (LDS, 64hw x 128ci, row stride 130
// ushorts = 65 dwords -> bank stride 1), B = W bf16 (direct global, L2-hot).
// Scale s (gate*BN or 1) folded into Bt staging.

__device__ __forceinline__ void stage_bt(unsigned int* __restrict__ BtU,
                                         const unsigned short* __restrict__ A,
                                         int hw0, float s) {
    unsigned short* Bs = (unsigned short*)BtU;
    #pragma unroll
    for (int i = 0; i < 16; ++i) {
        int idx = threadIdx.x + i * 256;       // 4096 = 128ci x 32 hw-pairs
        int ci = idx >> 5, p = idx & 31;
        unsigned int raw = *(const unsigned int*)(A + (size_t)ci * PLANE + hw0 + 2 * p);
        Bs[(2 * p) * 130 + ci]     = f2us(us2f(raw) * s);
        Bs[(2 * p + 1) * 130 + ci] = f2us(us2f(raw >> 16) * s);
    }
}

__device__ __forceinline__ bf16x8 afrag(const unsigned int* __restrict__ BtU,
                                        int r, int ko2) {
    union { unsigned int u[4]; bf16x8 v; } f;
    #pragma unroll
    for (int j = 0; j < 4; ++j) f.u[j] = BtU[r * 65 + ko2 + j];
    return f.v;
}

// ---------------------------------- mid pw (A -> B, BN in W), MFMA
__global__ __launch_bounds__(256) void
k_pw_mid(const unsigned short* __restrict__ A4,
         const unsigned short* __restrict__ A5,
         const unsigned short* __restrict__ Wbf,
         const float* __restrict__ gates,
         unsigned short* __restrict__ B4, unsigned short* __restrict__ B5) {
    int blk = blockIdx.x;              // b*32 + opi*16 + hwt
    int hwt = blk & 15;
    int opi = (blk >> 4) & 1;
    int b = blk >> 5;
    if (gates[b * 8 + 4 + opi] == 0.f) return;
    int hw0 = hwt * 64;
    int wave = threadIdx.x >> 6, lane = threadIdx.x & 63;
    int q = lane >> 4, mm = lane & 15;
    int r = wave * 16 + mm;
    __shared__ unsigned int BtU[64 * 65];
    stage_bt(BtU, (opi ? A5 : A4) + (size_t)b * SAMP, hw0, 1.f);
    __syncthreads();
    const unsigned short* Wb = Wbf + opi * 16384;
    f32x4 acc[8];
    #pragma unroll
    for (int i = 0; i < 8; ++i) acc[i] = (f32x4){0.f, 0.f, 0.f, 0.f};
    #pragma unroll
    for (int kb = 0; kb < 4; ++kb) {
        bf16x8 a = afrag(BtU, r, kb * 16 + q * 4);
        #pragma unroll
        for (int nt = 0; nt < 8; ++nt) {
            bf16x8 bv = *(const bf16x8*)(Wb + (nt * 16 + mm) * CC + kb * 32 + q * 8);
            acc[nt] = __builtin_amdgcn_mfma_f32_16x16x32_bf16(a, bv, acc[nt], 0, 0, 0);
        }
    }
    unsigned short* ob = (opi ? B5 : B4) + (size_t)b * SAMP;
    int hwbase = hw0 + wave * 16 + q * 4;
    #pragma unroll
    for (int nt = 0; nt < 8; ++nt) {
        int co = nt * 16 + mm;
        uint2 pk;
        pk.x = (unsigned int)f2us(acc[nt][0]) | ((unsigned int)f2us(acc[nt][1]) << 16);
        pk.y = (unsigned int)f2us(acc[nt][2]) | ((unsigned int)f2us(acc[nt][3]) << 16);
        *(uint2*)(ob + (size_t)co * PLANE + hwbase) = pk;
    }
}

// ------------- final pw: gated instances (gs in Bt), float4 RMW into out
__global__ __launch_bounds__(256) void
k_pw_final(const unsigned short* __restrict__ P4,
           const unsigned short* __restrict__ P5,
           const unsigned short* __restrict__ P6,
           const unsigned short* __restrict__ P7,
           const unsigned short* __restrict__ Wbf,
           const float* __restrict__ gates,
           const int* __restrict__ cnum, const int* __restrict__ cops,
           float* __restrict__ out) {
    int blk = blockIdx.x;              // b*16 + hwt
    int hwt = blk & 15;
    int b = blk >> 4;
    int n = cnum[b];
    if (n == 0) return;                // out already holds pools/skip/zeros
    int hw0 = hwt * 64;
    int wave = threadIdx.x >> 6, lane = threadIdx.x & 63;
    int q = lane >> 4, mm = lane & 15;
    int r = wave * 16 + mm;
    __shared__ unsigned int BtU[64 * 65];
    f32x4 acc[8];
    #pragma unroll
    for (int i = 0; i < 8; ++i) acc[i] = (f32x4){0.f, 0.f, 0.f, 0.f};
    for (int t = 0; t < n; ++t) {
        int op = cops[b * 4 + t];
        float gs = gates[b * 8 + op] * BN_SCALE;
        const unsigned short* src;
        switch (op) {
            case 4:  src = P4; break;
            case 5:  src = P5; break;
            case 6:  src = P6; break;
            default: src = P7; break;
        }
        if (t) __syncthreads();
        stage_bt(BtU, src + (size_t)b * SAMP, hw0, gs);
        __syncthreads();
        const unsigned short* Wb = Wbf + (op - 2) * 16384;
        #pragma unroll
        for (int kb = 0; kb < 4; ++kb) {
            bf16x8 a = afrag(BtU, r, kb * 16 + q * 4);
            #pragma unroll
            for (int nt = 0; nt < 8; ++nt) {
                bf16x8 bv = *(const bf16x8*)(Wb + (nt * 16 + mm) * CC + kb * 32 + q * 8);
                acc[nt] = __builtin_amdgcn_mfma_f32_16x16x32_bf16(a, bv, acc[nt], 0, 0, 0);
            }
        }
    }
    int hwbase = hw0 + wave * 16 + q * 4;
    #pragma unroll
    for (int nt = 0; nt < 8; ++nt) {
        int co = nt * 16 + mm;
        float* p = out + (size_t)(b * CC + co) * PLANE + hwbase;
        float4 o = *(float4*)p;
        o.x += acc[nt][0]; o.y += acc[nt][1];
        o.z += acc[nt][2]; o.w += acc[nt][3];
        *(float4*)p = o;
    }
}

// ---------------------------------------------------------------- launch
extern "C" void kernel_launch(void* const* d_in, const int* in_sizes, int n_in,
                              void* d_out, int out_size, void* d_ws, size_t ws_size,
                              hipStream_t stream) {
    const float* x      = (const float*)d_in[0];
    const float* wlog   = (const float*)d_in[1];
    const float* sc3_d1 = (const float*)d_in[2];
    const float* sc3_p1 = (const float*)d_in[3];
    const float* sc3_d2 = (const float*)d_in[4];
    const float* sc3_p2 = (const float*)d_in[5];
    const float* sc5_d1 = (const float*)d_in[6];
    const float* sc5_p1 = (const float*)d_in[7];
    const float* sc5_d2 = (const float*)d_in[8];
    const float* sc5_p2 = (const float*)d_in[9];
    const float* dc3_d  = (const float*)d_in[10];
    const float* dc3_p  = (const float*)d_in[11];
    const float* dc5_d  = (const float*)d_in[12];
    const float* dc5_p  = (const float*)d_in[13];
    const void* topp    = d_in[14];

    float* out  = (float*)d_out;
    float* outw = out + NOUT0;

    float* gates = (float*)d_ws;
    int*   cnum  = (int*)((char*)d_ws + 2048);
    int*   cops  = (int*)((char*)d_ws + 2304);
    unsigned short* Wbf  = (unsigned short*)((char*)d_ws + 4096);   // 6*32KB
    unsigned short* base = (unsigned short*)((char*)d_ws + 200704);
    unsigned short* A4 = base;
    unsigned short* A5 = base + (size_t)NOUT0;
    unsigned short* B4 = base + (size_t)NOUT0 * 2;
    unsigned short* B5 = base + (size_t)NOUT0 * 3;
    unsigned short* P4 = base + (size_t)NOUT0 * 4;
    unsigned short* P5 = base + (size_t)NOUT0 * 5;
    unsigned short* P6 = base + (size_t)NOUT0 * 6;
    unsigned short* P7 = base + (size_t)NOUT0 * 7;

    k_gates<<<1, 64, 0, stream>>>(wlog, topp, gates, cnum, cops, outw);
    k_prep<<<384, 256, 0, stream>>>(sc3_p1, sc5_p1, sc3_p2, sc5_p2, dc3_p, dc5_p, Wbf);
    k_pools<<<BB * CC, 256, 0, stream>>>(x, gates, out);
    k_dw_first<<<BB * CC, 256, 0, stream>>>(x, sc3_d1, sc5_d1, dc3_d, dc5_d,
                                            gates, A4, A5, P6, P7);
    k_pw_mid<<<BB * 32, 256, 0, stream>>>(A4, A5, Wbf, gates, B4, B5);
    k_dw_second<<<BB * CC, 256, 0, stream>>>(B4, B5, sc3_d2, sc5_d2, gates, P4, P5);
    k_pw_final<<<BB * 16, 256, 0, stream>>>(P4, P5, P6, P7, Wbf,
                                            gates, cnum, cops, out);
}

// Round 10
// 191.851 us; speedup vs baseline: 1.0558x; 1.0558x over previous
//
#include <hip/hip_runtime.h>
#include <hip/hip_bf16.h>

// DARTS MixedOp. B=64, C=128, H=W=32. Per-sample top-k(2) masked-softmax gate
// over 8 ops. Inputs fp32, outputs fp32.
//
// R10: 7 -> 5 dispatches. k_front fuses pools+skip+out-init+first-dw (single
// x read, LDS raw+relu planes). k_gates_prep merges gate computation with pw
// weight fp32->bf16 prep. MFMA pw kernels unchanged from R9 (m=hw n=co,
// LROW=130 LDS transpose, direct-global W, float4 RMW).
//
// ws: gates @0 | cnum @2048 | cops @2304 | Wbf[6][128][128] bf16 @4096 |
// 8 bf16 bufs of 16.8MB @200704 (A4 A5 B4 B5 P4 P5 P6 P7) = ~134MB.

#define BN_SCALE 0.9999950000374997f  // 1/sqrt(1+1e-5)
#define BB 64
#define CC 128
#define HH 32
#define WW 32
#define PLANE (HH*WW)          // 1024
#define SAMP (CC*PLANE)        // 131072
#define NOUT0 (BB*SAMP)        // 8388608

typedef __attribute__((ext_vector_type(8))) short bf16x8;
typedef __attribute__((ext_vector_type(4))) float f32x4;

__device__ __forceinline__ float us2f(unsigned int u) {
    unsigned int x = (u & 0xffffu) << 16;
    float f; __builtin_memcpy(&f, &x, 4); return f;
}
__device__ __forceinline__ unsigned short f2us(float f) {
    __hip_bfloat16 h = __float2bfloat16(f);
    unsigned short u; __builtin_memcpy(&u, &h, 2); return u;
}

// ---------------------------- gates (block 0) + weight prep (blocks 1..384)
__global__ __launch_bounds__(256) void
k_gates_prep(const float* __restrict__ wlog,
             const void* __restrict__ topp,
             const float* __restrict__ w0, const float* __restrict__ w1,
             const float* __restrict__ w2, const float* __restrict__ w3,
             const float* __restrict__ w4, const float* __restrict__ w5,
             float* __restrict__ gates,
             int* __restrict__ cnum, int* __restrict__ cops,
             float* __restrict__ out_w,
             unsigned short* __restrict__ Wbf) {
    if (blockIdx.x != 0) {
        int idx = (blockIdx.x - 1) * 256 + threadIdx.x;   // 6*16384 = 384*256
        int mat = idx >> 14, e = idx & 16383;
        const float* src; float s = 1.f;
        switch (mat) {                               // block-uniform
            case 0:  src = w0; s = BN_SCALE; break;  // sc3_p1 (mid, BN folded)
            case 1:  src = w1; s = BN_SCALE; break;  // sc5_p1
            case 2:  src = w2; break;                // sc3_p2 (gs in Bt)
            case 3:  src = w3; break;                // sc5_p2
            case 4:  src = w4; break;                // dc3_p
            default: src = w5; break;                // dc5_p
        }
        Wbf[idx] = f2us(src[e] * s);
        return;
    }
    if (threadIdx.x >= BB) return;
    int b = threadIdx.x;

    int top = -1;                           // robust `top` parse
    {
        unsigned int u0 = *(const unsigned int*)topp;
        int i32 = (int)u0;
        if (i32 >= 1 && i32 <= 8) top = i32;
        else {
            float f32; __builtin_memcpy(&f32, &u0, 4);
            if (f32 >= 1.f && f32 <= 8.f) top = (int)(f32 + 0.5f);
            else { float fb = us2f(u0); if (fb >= 1.f && fb <= 8.f) top = (int)(fb + 0.5f); }
        }
        if (top < 1 || top > 8) top = 2;
    }

    float lw[8];
    #pragma unroll
    for (int i = 0; i < 8; ++i) {
        lw[i] = wlog[b * 8 + i];
        out_w[b * 8 + i] = lw[i];           // output 1: clone of logits
    }
    bool sel[8] = {false,false,false,false,false,false,false,false};
    for (int t = 0; t < top; ++t) {         // lax.top_k tie-break: lowest index
        int best = -1; float bv = -3.4e38f;
        #pragma unroll
        for (int i = 0; i < 8; ++i)
            if (!sel[i] && lw[i] > bv) { bv = lw[i]; best = i; }
        if (best >= 0) sel[best] = true;
    }
    float m = -3.4e38f;
    #pragma unroll
    for (int i = 0; i < 8; ++i) if (sel[i] && lw[i] > m) m = lw[i];
    float s = 0.f, e[8];
    #pragma unroll
    for (int i = 0; i < 8; ++i) { e[i] = sel[i] ? expf(lw[i] - m) : 0.f; s += e[i]; }
    float inv = (s > 0.f) ? 1.f / s : 0.f;
    float g[8];
    #pragma unroll
    for (int i = 0; i < 8; ++i) {
        g[i] = (s > 0.f) ? e[i] * inv : (sel[i] ? 1.f / (float)top : 0.f);
        gates[b * 8 + i] = g[i];
    }
    int n = 0;
    #pragma unroll
    for (int i = 4; i < 8; ++i)
        if (g[i] > 0.f) { if (n < 4) cops[b * 4 + n] = i; ++n; }
    cnum[b] = (n < 4) ? n : 4;
}

// ------------------------------------------- depthwise conv helper
template <int K, int DIL>
__device__ __forceinline__ void dw_comp(const float* __restrict__ sx,
                                        const float* __restrict__ wd, int c,
                                        unsigned short* __restrict__ opp) {
    constexpr int PAD = (K / 2) * DIL;
    float wk[K * K];
    #pragma unroll
    for (int i = 0; i < K * K; ++i) wk[i] = wd[c * K * K + i];
    #pragma unroll
    for (int j = 0; j < 4; ++j) {
        int px = threadIdx.x + j * 256;
        int h = px >> 5, w = px & 31;
        float acc = 0.f;
        #pragma unroll
        for (int ky = 0; ky < K; ++ky) {
            int ih = h + ky * DIL - PAD;
            if ((unsigned)ih >= HH) continue;
            #pragma unroll
            for (int kx = 0; kx < K; ++kx) {
                int iw = w + kx * DIL - PAD;
                if ((unsigned)iw >= WW) continue;
                acc = fmaf(wk[ky * K + kx], sx[ih * WW + iw], acc);
            }
        }
        opp[px] = f2us(acc);
    }
}

// ------- front: pools + skip + out init + first dw of all 4 conv ops
__global__ __launch_bounds__(256) void
k_front(const float* __restrict__ x,
        const float* __restrict__ w4, const float* __restrict__ w5,
        const float* __restrict__ w6, const float* __restrict__ w7,
        const float* __restrict__ gates,
        float* __restrict__ out,
        unsigned short* __restrict__ A4, unsigned short* __restrict__ A5,
        unsigned short* __restrict__ P6, unsigned short* __restrict__ P7) {
    int plane = blockIdx.x;            // b*128 + c
    int b = plane >> 7, c = plane & 127;
    float g1 = gates[b * 8 + 1] * BN_SCALE;
    float g2 = gates[b * 8 + 2] * BN_SCALE;
    float g3 = gates[b * 8 + 3];
    float g4 = gates[b * 8 + 4], g5 = gates[b * 8 + 5];
    float g6 = gates[b * 8 + 6], g7 = gates[b * 8 + 7];
    bool haspool = (g1 != 0.f) | (g2 != 0.f) | (g3 != 0.f);
    bool hasdw   = (g4 != 0.f) | (g5 != 0.f) | (g6 != 0.f) | (g7 != 0.f);
    float* op = out + (size_t)plane * PLANE;
    if (!haspool && !hasdw) {
        ((float4*)op)[threadIdx.x] = make_float4(0.f, 0.f, 0.f, 0.f);
        return;
    }
    __shared__ float sxr[PLANE];       // raw x (pools/skip)
    __shared__ float sxf[PLANE];       // relu(x) (dw)
    {
        float4 v = ((const float4*)(x + (size_t)plane * PLANE))[threadIdx.x];
        ((float4*)sxr)[threadIdx.x] = v;
        ((float4*)sxf)[threadIdx.x] =
            make_float4(fmaxf(v.x, 0.f), fmaxf(v.y, 0.f),
                        fmaxf(v.z, 0.f), fmaxf(v.w, 0.f));
    }
    __syncthreads();

    // ---- out init: pools + skip (or zeros)
    if (haspool) {
        #pragma unroll
        for (int j = 0; j < 4; ++j) {
            int px = threadIdx.x + j * 256;
            int h = px >> 5, w = px & 31;
            float mx = -3.4e38f, sm = 0.f;
            int cnt = 0;
            #pragma unroll
            for (int dh = -1; dh <= 1; ++dh) {
                int ih = h + dh;
                if ((unsigned)ih >= HH) continue;
                #pragma unroll
                for (int dw = -1; dw <= 1; ++dw) {
                    int iw = w + dw;
                    if ((unsigned)iw >= WW) continue;
                    float v = sxr[ih * WW + iw];
                    mx = fmaxf(mx, v);
                    sm += v;
                    ++cnt;
                }
            }
            op[px] = g1 * mx + g2 * (sm / (float)cnt) + g3 * sxr[px];
        }
    } else {
        ((float4*)op)[threadIdx.x] = make_float4(0.f, 0.f, 0.f, 0.f);
    }

    // ---- first dw for gated conv ops
    size_t off = (size_t)plane * PLANE;
    if (g4 != 0.f) dw_comp<3, 1>(sxf, w4, c, A4 + off);
    if (g5 != 0.f) dw_comp<5, 1>(sxf, w5, c, A5 + off);
    if (g6 != 0.f) dw_comp<3, 2>(sxf, w6, c, P6 + off);
    if (g7 != 0.f) dw_comp<5, 2>(sxf, w7, c, P7 + off);
}

// ---------------------------------- second dw for sep ops (from bufB)
__global__ __launch_bounds__(256) void
k_dw_second(const unsigned short* __restrict__ B4,
            const unsigned short* __restrict__ B5,
            const float* __restrict__ w4, const float* __restrict__ w5,
            const float* __restrict__ gates,
            unsigned short* __restrict__ P4, unsigned short* __restrict__ P5) {
    int plane = blockIdx.x;            // b*128 + c
    int b = plane >> 7, c = plane & 127;
    float g4 = gates[b * 8 + 4], g5 = gates[b * 8 + 5];
    if (g4 == 0.f && g5 == 0.f) return;
    __shared__ float sx[PLANE];
    size_t off = (size_t)plane * PLANE;
    if (g4 != 0.f) {                       // block-uniform branch
        ushort4 v = ((const ushort4*)(B4 + off))[threadIdx.x];
        ((float4*)sx)[threadIdx.x] =
            make_float4(fmaxf(us2f(v.x), 0.f), fmaxf(us2f(v.y), 0.f),
                        fmaxf(us2f(v.z), 0.f), fmaxf(us2f(v.w), 0.f));
        __syncthreads();
        dw_comp<3, 1>(sx, w4, c, P4 + off);
        __syncthreads();
    }
    if (g5 != 0.f) {
        ushort4 v = ((const ushort4*)(B5 + off))[threadIdx.x];
        ((float4*)sx)[threadIdx.x] =
            make_float4(fmaxf(us2f(v.x), 0.f), fmaxf(us2f(v.y), 0.f),
                        fmaxf(us2f(v.z), 0.f), fmaxf(us2f(v.w), 0.f));
        __syncthreads();
        dw_comp<5, 1>(sx, w5, c, P5 + off);
    }
}

// ---------------- MFMA pw building blocks (R9) ---------------------------
// Orientation: m=hw, n=co. A = In^T tile (LDS, 64hw x 128ci, row stride 130
// ushorts = 65 dwords -> bank stride 1), B = W bf16 (direct global, L2-hot).

__device__ __forceinline__ void stage_bt(unsigned int* __restrict__ BtU,
                                         const unsigned short* __restrict__ A,
                                         int hw0, float s) {
    unsigned short* Bs = (unsigned short*)BtU;
    #pragma unroll
    for (int i = 0; i < 16; ++i) {
        int idx = threadIdx.x + i * 256;       // 4096 = 128ci x 32 hw-pairs
        int ci = idx >> 5, p = idx & 31;
        unsigned int raw = *(const unsigned int*)(A + (size_t)ci * PLANE + hw0 + 2 * p);
        Bs[(2 * p) * 130 + ci]     = f2us(us2f(raw) * s);
        Bs[(2 * p + 1) * 130 + ci] = f2us(us2f(raw >> 16) * s);
    }
}

__device__ __forceinline__ bf16x8 afrag(const unsigned int* __restrict__ BtU,
                                        int r, int ko2) {
    union { unsigned int u[4]; bf16x8 v; } f;
    #pragma unroll
    for (int j = 0; j < 4; ++j) f.u[j] = BtU[r * 65 + ko2 + j];
    return f.v;
}

// ---------------------------------- mid pw (A -> B, BN in W), MFMA
__global__ __launch_bounds__(256) void
k_pw_mid(const unsigned short* __restrict__ A4,
         const unsigned short* __restrict__ A5,
         const unsigned short* __restrict__ Wbf,
         const float* __restrict__ gates,
         unsigned short* __restrict__ B4, unsigned short* __restrict__ B5) {
    int blk = blockIdx.x;              // b*32 + opi*16 + hwt
    int hwt = blk & 15;
    int opi = (blk >> 4) & 1;
    int b = blk >> 5;
    if (gates[b * 8 + 4 + opi] == 0.f) return;
    int hw0 = hwt * 64;
    int wave = threadIdx.x >> 6, lane = threadIdx.x & 63;
    int q = lane >> 4, mm = lane & 15;
    int r = wave * 16 + mm;
    __shared__ unsigned int BtU[64 * 65];
    stage_bt(BtU, (opi ? A5 : A4) + (size_t)b * SAMP, hw0, 1.f);
    __syncthreads();
    const unsigned short* Wb = Wbf + opi * 16384;
    f32x4 acc[8];
    #pragma unroll
    for (int i = 0; i < 8; ++i) acc[i] = (f32x4){0.f, 0.f, 0.f, 0.f};
    #pragma unroll
    for (int kb = 0; kb < 4; ++kb) {
        bf16x8 a = afrag(BtU, r, kb * 16 + q * 4);
        #pragma unroll
        for (int nt = 0; nt < 8; ++nt) {
            bf16x8 bv = *(const bf16x8*)(Wb + (nt * 16 + mm) * CC + kb * 32 + q * 8);
            acc[nt] = __builtin_amdgcn_mfma_f32_16x16x32_bf16(a, bv, acc[nt], 0, 0, 0);
        }
    }
    unsigned short* ob = (opi ? B5 : B4) + (size_t)b * SAMP;
    int hwbase = hw0 + wave * 16 + q * 4;
    #pragma unroll
    for (int nt = 0; nt < 8; ++nt) {
        int co = nt * 16 + mm;
        uint2 pk;
        pk.x = (unsigned int)f2us(acc[nt][0]) | ((unsigned int)f2us(acc[nt][1]) << 16);
        pk.y = (unsigned int)f2us(acc[nt][2]) | ((unsigned int)f2us(acc[nt][3]) << 16);
        *(uint2*)(ob + (size_t)co * PLANE + hwbase) = pk;
    }
}

// ------------- final pw: gated instances (gs in Bt), float4 RMW into out
__global__ __launch_bounds__(256) void
k_pw_final(const unsigned short* __restrict__ P4,
           const unsigned short* __restrict__ P5,
           const unsigned short* __restrict__ P6,
           const unsigned short* __restrict__ P7,
           const unsigned short* __restrict__ Wbf,
           const float* __restrict__ gates,
           const int* __restrict__ cnum, const int* __restrict__ cops,
           float* __restrict__ out) {
    int blk = blockIdx.x;              // b*16 + hwt
    int hwt = blk & 15;
    int b = blk >> 4;
    int n = cnum[b];
    if (n == 0) return;                // out already holds pools/skip/zeros
    int hw0 = hwt * 64;
    int wave = threadIdx.x >> 6, lane = threadIdx.x & 63;
    int q = lane >> 4, mm = lane & 15;
    int r = wave * 16 + mm;
    __shared__ unsigned int BtU[64 * 65];
    f32x4 acc[8];
    #pragma unroll
    for (int i = 0; i < 8; ++i) acc[i] = (f32x4){0.f, 0.f, 0.f, 0.f};
    for (int t = 0; t < n; ++t) {
        int op = cops[b * 4 + t];
        float gs = gates[b * 8 + op] * BN_SCALE;
        const unsigned short* src;
        switch (op) {
            case 4:  src = P4; break;
            case 5:  src = P5; break;
            case 6:  src = P6; break;
            default: src = P7; break;
        }
        if (t) __syncthreads();
        stage_bt(BtU, src + (size_t)b * SAMP, hw0, gs);
        __syncthreads();
        const unsigned short* Wb = Wbf + (op - 2) * 16384;
        #pragma unroll
        for (int kb = 0; kb < 4; ++kb) {
            bf16x8 a = afrag(BtU, r, kb * 16 + q * 4);
            #pragma unroll
            for (int nt = 0; nt < 8; ++nt) {
                bf16x8 bv = *(const bf16x8*)(Wb + (nt * 16 + mm) * CC + kb * 32 + q * 8);
                acc[nt] = __builtin_amdgcn_mfma_f32_16x16x32_bf16(a, bv, acc[nt], 0, 0, 0);
            }
        }
    }
    int hwbase = hw0 + wave * 16 + q * 4;
    #pragma unroll
    for (int nt = 0; nt < 8; ++nt) {
        int co = nt * 16 + mm;
        float* p = out + (size_t)(b * CC + co) * PLANE + hwbase;
        float4 o = *(float4*)p;
        o.x += acc[nt][0]; o.y += acc[nt][1];
        o.z += acc[nt][2]; o.w += acc[nt][3];
        *(float4*)p = o;
    }
}

// ---------------------------------------------------------------- launch
extern "C" void kernel_launch(void* const* d_in, const int* in_sizes, int n_in,
                              void* d_out, int out_size, void* d_ws, size_t ws_size,
                              hipStream_t stream) {
    const float* x      = (const float*)d_in[0];
    const float* wlog   = (const float*)d_in[1];
    const float* sc3_d1 = (const float*)d_in[2];
    const float* sc3_p1 = (const float*)d_in[3];
    const float* sc3_d2 = (const float*)d_in[4];
    const float* sc3_p2 = (const float*)d_in[5];
    const float* sc5_d1 = (const float*)d_in[6];
    const float* sc5_p1 = (const float*)d_in[7];
    const float* sc5_d2 = (const float*)d_in[8];
    const float* sc5_p2 = (const float*)d_in[9];
    const float* dc3_d  = (const float*)d_in[10];
    const float* dc3_p  = (const float*)d_in[11];
    const float* dc5_d  = (const float*)d_in[12];
    const float* dc5_p  = (const float*)d_in[13];
    const void* topp    = d_in[14];

    float* out  = (float*)d_out;
    float* outw = out + NOUT0;

    float* gates = (float*)d_ws;
    int*   cnum  = (int*)((char*)d_ws + 2048);
    int*   cops  = (int*)((char*)d_ws + 2304);
    unsigned short* Wbf  = (unsigned short*)((char*)d_ws + 4096);   // 6*32KB
    unsigned short* base = (unsigned short*)((char*)d_ws + 200704);
    unsigned short* A4 = base;
    unsigned short* A5 = base + (size_t)NOUT0;
    unsigned short* B4 = base + (size_t)NOUT0 * 2;
    unsigned short* B5 = base + (size_t)NOUT0 * 3;
    unsigned short* P4 = base + (size_t)NOUT0 * 4;
    unsigned short* P5 = base + (size_t)NOUT0 * 5;
    unsigned short* P6 = base + (size_t)NOUT0 * 6;
    unsigned short* P7 = base + (size_t)NOUT0 * 7;

    k_gates_prep<<<385, 256, 0, stream>>>(wlog, topp,
                                          sc3_p1, sc5_p1, sc3_p2, sc5_p2,
                                          dc3_p, dc5_p,
                                          gates, cnum, cops, outw, Wbf);
    k_front<<<BB * CC, 256, 0, stream>>>(x, sc3_d1, sc5_d1, dc3_d, dc5_d,
                                         gates, out, A4, A5, P6, P7);
    k_pw_mid<<<BB * 32, 256, 0, stream>>>(A4, A5, Wbf, gates, B4, B5);
    k_dw_second<<<BB * CC, 256, 0, stream>>>(B4, B5, sc3_d2, sc5_d2, gates, P4, P5);
    k_pw_final<<<BB * 16, 256, 0, stream>>>(P4, P5, P6, P7, Wbf,
                                            gates, cnum, cops, out);
}